// Round 2
// baseline (22.470 us; speedup 1.0000x reference)
//
#include <hip/hip_runtime.h>

#define RPB 4        // rows per block; 1408 = 352 * 4
#define D   256      // LN / fc input dim
#define F   128      // fc output dim
#define C   10       // classes
#define LN_EPS 1e-5f

__global__ __launch_bounds__(256, 2) void logreg_fused(
    const float* __restrict__ seq,   const float* __restrict__ ln_g,
    const float* __restrict__ ln_b,  const float* __restrict__ fc_w,
    const float* __restrict__ fc_b,  const float* __restrict__ mlp_w,
    const float* __restrict__ mlp_b, float* __restrict__ out)
{
    __shared__ float4 sxn4[RPB][D / 4];   // normalized rows (float4 layout)
    __shared__ float  sh[RPB][F + 1];     // sigmoid outputs; +1 pad breaks 128-stride banks

    const int t    = threadIdx.x;
    const int wave = t >> 6;
    const int lane = t & 63;
    const int rowbase = blockIdx.x * RPB;

    // ---------- Phase 1: LayerNorm. Wave w handles row w. ----------
    {
        const float4 gv = ((const float4*)ln_g)[lane];
        const float4 bv = ((const float4*)ln_b)[lane];
        float4 v = ((const float4*)(seq + (size_t)(rowbase + wave) * D))[lane];
        float s  = v.x + v.y + v.z + v.w;
        float ss = v.x * v.x + v.y * v.y + v.z * v.z + v.w * v.w;
        #pragma unroll
        for (int off = 32; off > 0; off >>= 1) {
            s  += __shfl_xor(s,  off);
            ss += __shfl_xor(ss, off);
        }
        const float mean = s * (1.0f / D);
        const float var  = ss * (1.0f / D) - mean * mean;
        const float inv  = rsqrtf(var + LN_EPS);
        float4 o4;
        o4.x = (v.x - mean) * inv * gv.x + bv.x;
        o4.y = (v.y - mean) * inv * gv.y + bv.y;
        o4.z = (v.z - mean) * inv * gv.z + bv.z;
        o4.w = (v.w - mean) * inv * gv.w + bv.w;
        sxn4[wave][lane] = o4;
    }
    __syncthreads();

    // ---------- Phase 2: fc 256->128 GEMV + sigmoid. ----------
    // Thread t: output feature o = t & 127, rows {2*half, 2*half+1}.
    {
        const int o    = t & 127;
        const int half = t >> 7;      // wave-uniform (waves 0,1 -> 0; waves 2,3 -> 1)
        const int r0   = half * 2;
        const float bias = fc_b[o];
        float acc0 = bias, acc1 = bias;
        const float4* __restrict__ wrow = (const float4*)(fc_w + (size_t)o * D);
        #pragma unroll
        for (int kc = 0; kc < D / 4; kc += 8) {
            float4 w[8];
            #pragma unroll
            for (int j = 0; j < 8; ++j) w[j] = wrow[kc + j];
            #pragma unroll
            for (int j = 0; j < 8; ++j) {
                const float4 x0 = sxn4[r0][kc + j];       // uniform addr -> LDS broadcast
                acc0 += w[j].x * x0.x + w[j].y * x0.y + w[j].z * x0.z + w[j].w * x0.w;
                const float4 x1 = sxn4[r0 + 1][kc + j];
                acc1 += w[j].x * x1.x + w[j].y * x1.y + w[j].z * x1.z + w[j].w * x1.w;
            }
        }
        sh[r0][o]     = 1.0f / (1.0f + __expf(-acc0));
        sh[r0 + 1][o] = 1.0f / (1.0f + __expf(-acc1));
    }
    __syncthreads();

    // ---------- Phase 3: mlp 128->10. Two threads per (row, class). ----------
    if (t < RPB * C * 2) {
        const int oid  = t >> 1;
        const int half = t & 1;
        const int r    = oid / C;
        const int c    = oid % C;
        const float* __restrict__ wrow = mlp_w + (size_t)c * F;
        float s = 0.0f;
        #pragma unroll
        for (int f = half * 64; f < half * 64 + 64; ++f)
            s += sh[r][f] * wrow[f];
        s += __shfl_xor(s, 1);       // combine the two halves
        if (half == 0)
            out[(size_t)(rowbase + r) * C + c] = s + mlp_b[c];
    }
}

extern "C" void kernel_launch(void* const* d_in, const int* in_sizes, int n_in,
                              void* d_out, int out_size, void* d_ws, size_t ws_size,
                              hipStream_t stream)
{
    const float* seq   = (const float*)d_in[0];
    const float* ln_g  = (const float*)d_in[1];
    const float* ln_b  = (const float*)d_in[2];
    const float* fc_w  = (const float*)d_in[3];
    const float* fc_b  = (const float*)d_in[4];
    const float* mlp_w = (const float*)d_in[5];
    const float* mlp_b = (const float*)d_in[6];
    float* out = (float*)d_out;

    const int n_rows = 1408;                 // 32*4*11
    const int grid   = n_rows / RPB;         // 352 blocks
    logreg_fused<<<grid, 256, 0, stream>>>(seq, ln_g, ln_b, fc_w, fc_b,
                                           mlp_w, mlp_b, out);
}

// Round 3
// 18.731 us; speedup vs baseline: 1.1996x; 1.1996x over previous
//
#include <hip/hip_runtime.h>

#define D   256      // LN / fc input dim
#define F   128      // fc output dim
#define C   10       // classes
#define LN_EPS 1e-5f

__global__ __launch_bounds__(256, 1) void logreg_fused(
    const float* __restrict__ seq,   const float* __restrict__ ln_g,
    const float* __restrict__ ln_b,  const float* __restrict__ fc_w,
    const float* __restrict__ fc_b,  const float* __restrict__ mlp_w,
    const float* __restrict__ mlp_b, float* __restrict__ out)
{
    __shared__ float4 sx[8][D / 4];   // normalized rows (float4 granules)
    __shared__ float  sh[8][F];       // sigmoid outputs (rows are wave-private)

    const int t    = threadIdx.x;
    const int w    = t >> 6;
    const int lane = t & 63;
    const int rowbase = blockIdx.x * 8;
    const int r0 = 2 * w, r1 = 2 * w + 1;

    // ---------- Phase 1: LayerNorm. Wave w owns rows r0, r1 (no barrier needed). ----------
    {
        const float4 gv = ((const float4*)ln_g)[lane];
        const float4 bv = ((const float4*)ln_b)[lane];
        #pragma unroll
        for (int rr = 0; rr < 2; ++rr) {
            const int r = 2 * w + rr;
            float4 v = ((const float4*)(seq + (size_t)(rowbase + r) * D))[lane];
            float s  = v.x + v.y + v.z + v.w;
            float ss = v.x * v.x + v.y * v.y + v.z * v.z + v.w * v.w;
            #pragma unroll
            for (int off = 32; off > 0; off >>= 1) {
                s  += __shfl_xor(s,  off);
                ss += __shfl_xor(ss, off);
            }
            const float mean = s * (1.0f / D);
            const float var  = ss * (1.0f / D) - mean * mean;
            const float inv  = rsqrtf(var + LN_EPS);
            float4 o4;
            o4.x = (v.x - mean) * inv * gv.x + bv.x;
            o4.y = (v.y - mean) * inv * gv.y + bv.y;
            o4.z = (v.z - mean) * inv * gv.z + bv.z;
            o4.w = (v.w - mean) * inv * gv.w + bv.w;
            sx[r][lane] = o4;
        }
    }
    // same-wave LDS RAW: in-order wave + compiler lgkmcnt, no __syncthreads.

    // ---------- Phase 2: fc 256->128 GEMV + sigmoid, 8-lane cooperative groups. ----------
    // group g = lane>>3 owns output o = s*8+g; lane j = lane&7 covers granules j+8i.
    {
        const int g = lane >> 3;
        const int j = lane & 7;

        // Hoist x for both rows: 16 float4 regs, reused across all 16 output-sets.
        float4 xa[8], xb[8];
        #pragma unroll
        for (int i = 0; i < 8; ++i) {
            xa[i] = sx[r0][j + 8 * i];   // 8 distinct granules, 8-way broadcast: conflict-free
            xb[i] = sx[r1][j + 8 * i];
        }

        #pragma unroll 2
        for (int s = 0; s < 16; ++s) {
            const int o = s * 8 + g;
            const float4* __restrict__ wr = (const float4*)(fc_w + (size_t)o * D);
            float4 wv[8];
            #pragma unroll
            for (int i = 0; i < 8; ++i) wv[i] = wr[j + 8 * i];  // 128B contiguous per row: 16 full lines/instr
            float pa = 0.0f, pb = 0.0f;
            #pragma unroll
            for (int i = 0; i < 8; ++i) {
                pa += wv[i].x * xa[i].x + wv[i].y * xa[i].y
                    + wv[i].z * xa[i].z + wv[i].w * xa[i].w;
                pb += wv[i].x * xb[i].x + wv[i].y * xb[i].y
                    + wv[i].z * xb[i].z + wv[i].w * xb[i].w;
            }
            // 3-level reduce across the 8-lane group
            pa += __shfl_xor(pa, 1); pb += __shfl_xor(pb, 1);
            pa += __shfl_xor(pa, 2); pb += __shfl_xor(pb, 2);
            pa += __shfl_xor(pa, 4); pb += __shfl_xor(pb, 4);
            if (j == 0) {
                const float bo = fc_b[o];
                sh[r0][o] = 1.0f / (1.0f + __expf(-(pa + bo)));
                sh[r1][o] = 1.0f / (1.0f + __expf(-(pb + bo)));
            }
        }
    }
    // wave-local again: this wave wrote all 128 outputs for its own rows.

    // ---------- Phase 3: mlp 128->10, full-wave reduce per (row, class). ----------
    {
        const float h0a = sh[r0][lane], h0b = sh[r0][lane + 64];
        const float h1a = sh[r1][lane], h1b = sh[r1][lane + 64];
        #pragma unroll
        for (int c = 0; c < C; ++c) {
            const float w2a = mlp_w[c * F + lane];
            const float w2b = mlp_w[c * F + lane + 64];
            float p0 = h0a * w2a + h0b * w2b;
            float p1 = h1a * w2a + h1b * w2b;
            #pragma unroll
            for (int off = 32; off > 0; off >>= 1) {
                p0 += __shfl_xor(p0, off);
                p1 += __shfl_xor(p1, off);
            }
            if (lane == 0) {
                const float bc = mlp_b[c];
                out[(size_t)(rowbase + r0) * C + c] = p0 + bc;
                out[(size_t)(rowbase + r1) * C + c] = p1 + bc;
            }
        }
    }
}

extern "C" void kernel_launch(void* const* d_in, const int* in_sizes, int n_in,
                              void* d_out, int out_size, void* d_ws, size_t ws_size,
                              hipStream_t stream)
{
    const float* seq   = (const float*)d_in[0];
    const float* ln_g  = (const float*)d_in[1];
    const float* ln_b  = (const float*)d_in[2];
    const float* fc_w  = (const float*)d_in[3];
    const float* fc_b  = (const float*)d_in[4];
    const float* mlp_w = (const float*)d_in[5];
    const float* mlp_b = (const float*)d_in[6];
    float* out = (float*)d_out;

    // 1408 rows = 176 blocks * 8 rows; one block per CU, zero barriers.
    logreg_fused<<<176, 256, 0, stream>>>(seq, ln_g, ln_b, fc_w, fc_b,
                                          mlp_w, mlp_b, out);
}

// Round 4
// 16.565 us; speedup vs baseline: 1.3565x; 1.1308x over previous
//
#include <hip/hip_runtime.h>

#define D   256      // LN / fc input dim
#define F   128      // fc output dim
#define C   10       // classes
#define LN_EPS 1e-5f

__global__ __launch_bounds__(256, 1) void logreg_fused(
    const float* __restrict__ seq,   const float* __restrict__ ln_g,
    const float* __restrict__ ln_b,  const float* __restrict__ fc_w,
    const float* __restrict__ fc_b,  const float* __restrict__ mlp_w,
    const float* __restrict__ mlp_b, float* __restrict__ out)
{
    __shared__ float4 sx[8][D / 4];   // 8 normalized rows (float4 granules), 8 KB
    __shared__ float  sh[8][F];       // sigmoid outputs, 4 KB

    const int t    = threadIdx.x;
    const int w    = t >> 6;
    const int lane = t & 63;
    const int rowbase = blockIdx.x * 8;

    // ---------- Phase 1: LayerNorm. Wave w handles rows 2w, 2w+1. ----------
    {
        const float4 gv = ((const float4*)ln_g)[lane];
        const float4 bv = ((const float4*)ln_b)[lane];
        #pragma unroll
        for (int rr = 0; rr < 2; ++rr) {
            const int r = 2 * w + rr;
            float4 v = ((const float4*)(seq + (size_t)(rowbase + r) * D))[lane];
            float s  = v.x + v.y + v.z + v.w;
            float ss = v.x * v.x + v.y * v.y + v.z * v.z + v.w * v.w;
            #pragma unroll
            for (int off = 32; off > 0; off >>= 1) {
                s  += __shfl_xor(s,  off);
                ss += __shfl_xor(ss, off);
            }
            const float mean = s * (1.0f / D);
            const float var  = ss * (1.0f / D) - mean * mean;
            const float inv  = rsqrtf(var + LN_EPS);
            float4 o4;
            o4.x = (v.x - mean) * inv * gv.x + bv.x;
            o4.y = (v.y - mean) * inv * gv.y + bv.y;
            o4.z = (v.z - mean) * inv * gv.z + bv.z;
            o4.w = (v.w - mean) * inv * gv.w + bv.w;
            sx[r][lane] = o4;
        }
    }
    __syncthreads();

    // ---------- Phase 2: fc 256->128. Wave w owns outputs [32w, 32w+32) for ALL 8 rows.
    // fc_w is read exactly ONCE per block (128 KB). 8-lane group g covers output
    // o = 32w + 8s + g; lane j = lane&7 covers k-granules j + 8i.
    {
        const int g     = lane >> 3;
        const int j     = lane & 7;
        const int obase = 32 * w;

        float pa[4][8];
        #pragma unroll
        for (int s = 0; s < 4; ++s)
            #pragma unroll
            for (int r = 0; r < 8; ++r) pa[s][r] = 0.0f;

        #pragma unroll
        for (int ih = 0; ih < 2; ++ih) {           // two k-halves to bound VGPRs
            float4 wv[4][4];
            #pragma unroll
            for (int s = 0; s < 4; ++s) {
                const float4* __restrict__ wr =
                    (const float4*)(fc_w + (size_t)(obase + 8 * s + g) * D);
                #pragma unroll
                for (int ii = 0; ii < 4; ++ii)
                    wv[s][ii] = wr[j + 8 * (4 * ih + ii)];  // 128B contiguous per row
            }
            #pragma unroll
            for (int ii = 0; ii < 4; ++ii) {
                const int i = 4 * ih + ii;
                float4 xr[8];
                #pragma unroll
                for (int r = 0; r < 8; ++r)
                    xr[r] = sx[r][j + 8 * i];      // 8 granules x 8-way broadcast: conflict-free
                #pragma unroll
                for (int s = 0; s < 4; ++s)
                    #pragma unroll
                    for (int r = 0; r < 8; ++r)
                        pa[s][r] += wv[s][ii].x * xr[r].x + wv[s][ii].y * xr[r].y
                                  + wv[s][ii].z * xr[r].z + wv[s][ii].w * xr[r].w;
            }
        }

        // reduce each accumulator across the 8-lane group
        #pragma unroll
        for (int s = 0; s < 4; ++s)
            #pragma unroll
            for (int r = 0; r < 8; ++r) {
                float p = pa[s][r];
                p += __shfl_xor(p, 1);
                p += __shfl_xor(p, 2);
                p += __shfl_xor(p, 4);
                pa[s][r] = p;
            }
        if (j == 0) {
            #pragma unroll
            for (int s = 0; s < 4; ++s) {
                const int o  = obase + 8 * s + g;
                const float bo = fc_b[o];
                #pragma unroll
                for (int r = 0; r < 8; ++r)
                    sh[r][o] = 1.0f / (1.0f + __expf(-(pa[s][r] + bo)));
            }
        }
    }
    __syncthreads();

    // ---------- Phase 3: mlp 128->10, full-wave reduce; wave w -> rows 2w, 2w+1. ----------
    {
        const int r0 = 2 * w, r1 = 2 * w + 1;
        const float h0a = sh[r0][lane], h0b = sh[r0][lane + 64];
        const float h1a = sh[r1][lane], h1b = sh[r1][lane + 64];
        #pragma unroll
        for (int c = 0; c < C; ++c) {
            const float w2a = mlp_w[c * F + lane];
            const float w2b = mlp_w[c * F + lane + 64];
            float p0 = h0a * w2a + h0b * w2b;
            float p1 = h1a * w2a + h1b * w2b;
            #pragma unroll
            for (int off = 32; off > 0; off >>= 1) {
                p0 += __shfl_xor(p0, off);
                p1 += __shfl_xor(p1, off);
            }
            if (lane == 0) {
                const float bc = mlp_b[c];
                out[(size_t)(rowbase + r0) * C + c] = p0 + bc;
                out[(size_t)(rowbase + r1) * C + c] = p1 + bc;
            }
        }
    }
}

extern "C" void kernel_launch(void* const* d_in, const int* in_sizes, int n_in,
                              void* d_out, int out_size, void* d_ws, size_t ws_size,
                              hipStream_t stream)
{
    const float* seq   = (const float*)d_in[0];
    const float* ln_g  = (const float*)d_in[1];
    const float* ln_b  = (const float*)d_in[2];
    const float* fc_w  = (const float*)d_in[3];
    const float* fc_b  = (const float*)d_in[4];
    const float* mlp_w = (const float*)d_in[5];
    const float* mlp_b = (const float*)d_in[6];
    float* out = (float*)d_out;

    // 1408 rows = 176 blocks * 8 rows; one block per CU.
    logreg_fused<<<176, 256, 0, stream>>>(seq, ln_g, ln_b, fc_w, fc_b,
                                          mlp_w, mlp_b, out);
}

// Round 5
// 16.204 us; speedup vs baseline: 1.3867x; 1.0223x over previous
//
#include <hip/hip_runtime.h>

#define D   256      // LN / fc input dim
#define F   128      // fc output dim
#define C   10       // classes
#define LN_EPS 1e-5f

__global__ __launch_bounds__(256, 1) void logreg_fused(
    const float* __restrict__ seq,   const float* __restrict__ ln_g,
    const float* __restrict__ ln_b,  const float* __restrict__ fc_w,
    const float* __restrict__ fc_b,  const float* __restrict__ mlp_w,
    const float* __restrict__ mlp_b, float* __restrict__ out)
{
    __shared__ float4 sx[8][D / 4];   // 8 normalized rows, 8 KB
    __shared__ float  sh[8][F];       // sigmoid outputs, 4 KB

    const int t    = threadIdx.x;
    const int w    = t >> 6;
    const int lane = t & 63;
    const int rowbase = blockIdx.x * 8;
    const int g     = lane >> 3;      // 8-lane group -> output
    const int j     = lane & 7;       // k-chunk within group
    const int obase = 32 * w;

    // ---------- Issue order: seq first (LN consumes it soon), then ALL weight
    // prefetches (consumed much later -> latency hidden under LN).
    float4 v0 = ((const float4*)(seq + (size_t)(rowbase + 2 * w)     * D))[lane];
    float4 v1 = ((const float4*)(seq + (size_t)(rowbase + 2 * w + 1) * D))[lane];
    const float4 gv = ((const float4*)ln_g)[lane];
    const float4 bv = ((const float4*)ln_b)[lane];

    // fc_w: 32 float4/thread, 128B contiguous per output row per wave instr.
    float4 wv[4][8];
    #pragma unroll
    for (int s = 0; s < 4; ++s) {
        const float4* __restrict__ wr =
            (const float4*)(fc_w + (size_t)(obase + 8 * s + g) * D);
        #pragma unroll
        for (int i = 0; i < 8; ++i) wv[s][i] = wr[j + 8 * i];
    }
    float fcb[4];
    #pragma unroll
    for (int s = 0; s < 4; ++s) fcb[s] = fc_b[obase + 8 * s + g];
    float w2a[C], w2b[C], mb[C];
    #pragma unroll
    for (int c = 0; c < C; ++c) {
        w2a[c] = mlp_w[c * F + lane];
        w2b[c] = mlp_w[c * F + lane + 64];
        mb[c]  = mlp_b[c];
    }

    // ---------- Phase 1: LayerNorm (rows 2w, 2w+1), runs while prefetches fly.
    {
        float s0 = v0.x + v0.y + v0.z + v0.w;
        float q0 = v0.x * v0.x + v0.y * v0.y + v0.z * v0.z + v0.w * v0.w;
        float s1 = v1.x + v1.y + v1.z + v1.w;
        float q1 = v1.x * v1.x + v1.y * v1.y + v1.z * v1.z + v1.w * v1.w;
        #pragma unroll
        for (int off = 32; off > 0; off >>= 1) {
            s0 += __shfl_xor(s0, off);  q0 += __shfl_xor(q0, off);
            s1 += __shfl_xor(s1, off);  q1 += __shfl_xor(q1, off);
        }
        const float m0 = s0 * (1.0f / D), m1 = s1 * (1.0f / D);
        const float i0 = rsqrtf(q0 * (1.0f / D) - m0 * m0 + LN_EPS);
        const float i1 = rsqrtf(q1 * (1.0f / D) - m1 * m1 + LN_EPS);
        float4 o0, o1;
        o0.x = (v0.x - m0) * i0 * gv.x + bv.x;  o1.x = (v1.x - m1) * i1 * gv.x + bv.x;
        o0.y = (v0.y - m0) * i0 * gv.y + bv.y;  o1.y = (v1.y - m1) * i1 * gv.y + bv.y;
        o0.z = (v0.z - m0) * i0 * gv.z + bv.z;  o1.z = (v1.z - m1) * i1 * gv.z + bv.z;
        o0.w = (v0.w - m0) * i0 * gv.w + bv.w;  o1.w = (v1.w - m1) * i1 * gv.w + bv.w;
        sx[2 * w][lane]     = o0;
        sx[2 * w + 1][lane] = o1;
    }

    // LDS-only barrier: order sx writes/reads without draining vmcnt
    // (prefetched regs are thread-private -> no cross-thread vmem hazard).
    asm volatile("s_waitcnt lgkmcnt(0)" ::: "memory");
    __builtin_amdgcn_s_barrier();

    // ---------- Phase 2: fc 256->128. Wave w owns outputs [32w,32w+32) for all 8 rows.
    {
        float pa[4][8];
        #pragma unroll
        for (int s = 0; s < 4; ++s)
            #pragma unroll
            for (int r = 0; r < 8; ++r) pa[s][r] = 0.0f;

        #pragma unroll
        for (int i = 0; i < 8; ++i) {
            float4 xr[8];
            #pragma unroll
            for (int r = 0; r < 8; ++r)
                xr[r] = sx[r][j + 8 * i];      // 8-way broadcast, conflict-free
            #pragma unroll
            for (int s = 0; s < 4; ++s)
                #pragma unroll
                for (int r = 0; r < 8; ++r)
                    pa[s][r] += wv[s][i].x * xr[r].x + wv[s][i].y * xr[r].y
                              + wv[s][i].z * xr[r].z + wv[s][i].w * xr[r].w;
        }

        #pragma unroll
        for (int s = 0; s < 4; ++s)
            #pragma unroll
            for (int r = 0; r < 8; ++r) {
                float p = pa[s][r];
                p += __shfl_xor(p, 1);
                p += __shfl_xor(p, 2);
                p += __shfl_xor(p, 4);
                pa[s][r] = p;
            }
        if (j == 0) {
            #pragma unroll
            for (int s = 0; s < 4; ++s) {
                const int o = obase + 8 * s + g;
                #pragma unroll
                for (int r = 0; r < 8; ++r)
                    sh[r][o] = 1.0f / (1.0f + __expf(-(pa[s][r] + fcb[s])));
            }
        }
    }

    asm volatile("s_waitcnt lgkmcnt(0)" ::: "memory");
    __builtin_amdgcn_s_barrier();

    // ---------- Phase 3: mlp 128->10, full-wave reduce; wave w -> rows 2w, 2w+1.
    {
        const int r0 = 2 * w, r1 = 2 * w + 1;
        const float h0a = sh[r0][lane], h0b = sh[r0][lane + 64];
        const float h1a = sh[r1][lane], h1b = sh[r1][lane + 64];
        #pragma unroll
        for (int c = 0; c < C; ++c) {
            float p0 = h0a * w2a[c] + h0b * w2b[c];
            float p1 = h1a * w2a[c] + h1b * w2b[c];
            #pragma unroll
            for (int off = 32; off > 0; off >>= 1) {
                p0 += __shfl_xor(p0, off);
                p1 += __shfl_xor(p1, off);
            }
            if (lane == 0) {
                out[(size_t)(rowbase + r0) * C + c] = p0 + mb[c];
                out[(size_t)(rowbase + r1) * C + c] = p1 + mb[c];
            }
        }
    }
}

extern "C" void kernel_launch(void* const* d_in, const int* in_sizes, int n_in,
                              void* d_out, int out_size, void* d_ws, size_t ws_size,
                              hipStream_t stream)
{
    const float* seq   = (const float*)d_in[0];
    const float* ln_g  = (const float*)d_in[1];
    const float* ln_b  = (const float*)d_in[2];
    const float* fc_w  = (const float*)d_in[3];
    const float* fc_b  = (const float*)d_in[4];
    const float* mlp_w = (const float*)d_in[5];
    const float* mlp_b = (const float*)d_in[6];
    float* out = (float*)d_out;

    // 1408 rows = 176 blocks * 8 rows; one block per CU.
    logreg_fused<<<176, 256, 0, stream>>>(seq, ln_g, ln_b, fc_w, fc_b,
                                          mlp_w, mlp_b, out);
}

// Round 6
// 13.164 us; speedup vs baseline: 1.7069x; 1.2309x over previous
//
#include <hip/hip_runtime.h>
#include <hip/hip_bf16.h>

#define D   256      // LN / fc input dim
#define F   128      // fc output dim
#define C   10       // classes
#define LN_EPS 1e-5f

typedef __attribute__((ext_vector_type(8))) short short8;   // 8 bf16 = 4 VGPR
typedef __attribute__((ext_vector_type(4))) short short4v;  // 4 bf16 = 2 VGPR
typedef __attribute__((ext_vector_type(4))) float f32x4;    // MFMA acc

__device__ __forceinline__ short f2bf(float f) {
    __hip_bfloat16 h = __float2bfloat16(f);          // RNE
    return *reinterpret_cast<short*>(&h);
}
__device__ __forceinline__ short8 pack8(float4 a, float4 b) {
    short8 r;
    r[0] = f2bf(a.x); r[1] = f2bf(a.y); r[2] = f2bf(a.z); r[3] = f2bf(a.w);
    r[4] = f2bf(b.x); r[5] = f2bf(b.y); r[6] = f2bf(b.z); r[7] = f2bf(b.w);
    return r;
}

__global__ __launch_bounds__(256, 1) void logreg_fused(
    const float* __restrict__ seq,   const float* __restrict__ ln_g,
    const float* __restrict__ ln_b,  const float* __restrict__ fc_w,
    const float* __restrict__ fc_b,  const float* __restrict__ mlp_w,
    const float* __restrict__ mlp_b, float* __restrict__ out)
{
    // A-tile: 16 rows x 256 k, bf16, XOR-swizzled (byte ^= row<<4). Rows 8-15
    // are never written; their garbage only reaches D rows 8-15 (lanes 32-63),
    // which the epilogue skips. 8 KB.
    __shared__ short sxb[16 * D];
    __shared__ float sh[8][F];    // sigmoid outputs, 4 KB

    const int t    = threadIdx.x;
    const int w    = t >> 6;
    const int lane = t & 63;
    const int q    = lane >> 4;   // k-subgroup 0..3
    const int col  = lane & 15;   // fragment row/col index
    const int rowbase = blockIdx.x * 8;
    const int obase   = 32 * w;   // wave's 32 output columns

    // ---------- Issue order: seq first, then fc_w in B-fragment order. ----------
    float4 v0 = ((const float4*)(seq + (size_t)(rowbase + 2 * w)     * D))[lane];
    float4 v1 = ((const float4*)(seq + (size_t)(rowbase + 2 * w + 1) * D))[lane];
    const float4 gv = ((const float4*)ln_g)[lane];
    const float4 bv = ((const float4*)ln_b)[lane];

    // B-fragment prefetch: lane supplies B[k = 32kk+8q .. +8][col obase+16ts+col]
    // = fc_w[obase+16ts+col][32kk+8q .. +8] -> 2 float4 per (ts,kk).
    // Wave instr touches 16 rows x 1 full 128B line each: coalesced.
    float4 wf[2][16];
    #pragma unroll
    for (int ts = 0; ts < 2; ++ts) {
        const float4* __restrict__ wr =
            (const float4*)fc_w + (size_t)(obase + 16 * ts + col) * (D / 4) + 2 * q;
        #pragma unroll
        for (int kk = 0; kk < 8; ++kk) {
            wf[ts][2 * kk]     = wr[8 * kk];
            wf[ts][2 * kk + 1] = wr[8 * kk + 1];
        }
    }
    float fcb0 = fc_b[obase + col];
    float fcb1 = fc_b[obase + 16 + col];

    // ---------- Phase 1: LayerNorm (rows 2w, 2w+1) under the prefetch. ----------
    {
        float s0 = v0.x + v0.y + v0.z + v0.w;
        float q0 = v0.x * v0.x + v0.y * v0.y + v0.z * v0.z + v0.w * v0.w;
        float s1 = v1.x + v1.y + v1.z + v1.w;
        float q1 = v1.x * v1.x + v1.y * v1.y + v1.z * v1.z + v1.w * v1.w;
        #pragma unroll
        for (int off = 32; off > 0; off >>= 1) {
            s0 += __shfl_xor(s0, off);  q0 += __shfl_xor(q0, off);
            s1 += __shfl_xor(s1, off);  q1 += __shfl_xor(q1, off);
        }
        const float m0 = s0 * (1.0f / D), m1 = s1 * (1.0f / D);
        const float i0 = rsqrtf(q0 * (1.0f / D) - m0 * m0 + LN_EPS);
        const float i1 = rsqrtf(q1 * (1.0f / D) - m1 * m1 + LN_EPS);
        float4 o0, o1;
        o0.x = (v0.x - m0) * i0 * gv.x + bv.x;  o1.x = (v1.x - m1) * i1 * gv.x + bv.x;
        o0.y = (v0.y - m0) * i0 * gv.y + bv.y;  o1.y = (v1.y - m1) * i1 * gv.y + bv.y;
        o0.z = (v0.z - m0) * i0 * gv.z + bv.z;  o1.z = (v1.z - m1) * i1 * gv.z + bv.z;
        o0.w = (v0.w - m0) * i0 * gv.w + bv.w;  o1.w = (v1.w - m1) * i1 * gv.w + bv.w;

        // bf16 store, swizzled: byte = (r*512 + lane*8) ^ (r<<4)
        short4v a0, a1;
        a0[0] = f2bf(o0.x); a0[1] = f2bf(o0.y); a0[2] = f2bf(o0.z); a0[3] = f2bf(o0.w);
        a1[0] = f2bf(o1.x); a1[1] = f2bf(o1.y); a1[2] = f2bf(o1.z); a1[3] = f2bf(o1.w);
        const int r0 = 2 * w, r1 = 2 * w + 1;
        *(short4v*)((char*)sxb + (((r0 * 512) + lane * 8) ^ (r0 << 4))) = a0;
        *(short4v*)((char*)sxb + (((r1 * 512) + lane * 8) ^ (r1 << 4))) = a1;
    }

    // Convert B-fragments fp32 -> bf16 in regs (pairs fuse to v_cvt_pk_bf16_f32).
    short8 wb0[8], wb1[8];
    #pragma unroll
    for (int kk = 0; kk < 8; ++kk) {
        wb0[kk] = pack8(wf[0][2 * kk], wf[0][2 * kk + 1]);
        wb1[kk] = pack8(wf[1][2 * kk], wf[1][2 * kk + 1]);
    }

    // LDS-only barrier (keeps any remaining vmem in flight).
    asm volatile("s_waitcnt lgkmcnt(0)" ::: "memory");
    __builtin_amdgcn_s_barrier();

    // mlp prefetch here: plenty of slack before phase 3, keeps peak VGPR down.
    float w2a[C], w2b[C], mb[C];
    #pragma unroll
    for (int c = 0; c < C; ++c) {
        w2a[c] = mlp_w[c * F + lane];
        w2b[c] = mlp_w[c * F + lane + 64];
        mb[c]  = mlp_b[c];
    }

    // ---------- Phase 2: fc as MFMA. acc[ts] = x(16x256) . w^T(256x16ts) ----------
    f32x4 acc0 = {0.f, 0.f, 0.f, 0.f};
    f32x4 acc1 = {0.f, 0.f, 0.f, 0.f};
    #pragma unroll
    for (int kk = 0; kk < 8; ++kk) {
        // A-frag: row = col(=lane&15), k = 32kk + 8q .. +8; same swizzle as writer.
        const int boff = ((col * 512) + kk * 64 + q * 16) ^ (col << 4);
        short8 a = *(const short8*)((const char*)sxb + boff);
        acc0 = __builtin_amdgcn_mfma_f32_16x16x32_bf16(a, wb0[kk], acc0, 0, 0, 0);
        acc1 = __builtin_amdgcn_mfma_f32_16x16x32_bf16(a, wb1[kk], acc1, 0, 0, 0);
    }

    // Epilogue: D layout col=lane&15, row=(lane>>4)*4+reg (HW-verified m89).
    // Valid rows 0-7 live in lanes 0-31.
    if (lane < 32) {
        #pragma unroll
        for (int rg = 0; rg < 4; ++rg) {
            const int r = q * 4 + rg;          // q in {0,1} here
            sh[r][obase + col]      = 1.0f / (1.0f + __expf(-(acc0[rg] + fcb0)));
            sh[r][obase + 16 + col] = 1.0f / (1.0f + __expf(-(acc1[rg] + fcb1)));
        }
    }

    asm volatile("s_waitcnt lgkmcnt(0)" ::: "memory");
    __builtin_amdgcn_s_barrier();

    // ---------- Phase 3: mlp 128->10 fp32, full-wave reduce; wave w -> rows 2w,2w+1.
    {
        const int r0 = 2 * w, r1 = 2 * w + 1;
        const float h0a = sh[r0][lane], h0b = sh[r0][lane + 64];
        const float h1a = sh[r1][lane], h1b = sh[r1][lane + 64];
        #pragma unroll
        for (int c = 0; c < C; ++c) {
            float p0 = h0a * w2a[c] + h0b * w2b[c];
            float p1 = h1a * w2a[c] + h1b * w2b[c];
            #pragma unroll
            for (int off = 32; off > 0; off >>= 1) {
                p0 += __shfl_xor(p0, off);
                p1 += __shfl_xor(p1, off);
            }
            if (lane == 0) {
                out[(size_t)(rowbase + r0) * C + c] = p0 + mb[c];
                out[(size_t)(rowbase + r1) * C + c] = p1 + mb[c];
            }
        }
    }
}

extern "C" void kernel_launch(void* const* d_in, const int* in_sizes, int n_in,
                              void* d_out, int out_size, void* d_ws, size_t ws_size,
                              hipStream_t stream)
{
    const float* seq   = (const float*)d_in[0];
    const float* ln_g  = (const float*)d_in[1];
    const float* ln_b  = (const float*)d_in[2];
    const float* fc_w  = (const float*)d_in[3];
    const float* fc_b  = (const float*)d_in[4];
    const float* mlp_w = (const float*)d_in[5];
    const float* mlp_b = (const float*)d_in[6];
    float* out = (float*)d_out;

    // 1408 rows = 176 blocks * 8 rows; one block per CU.
    logreg_fused<<<176, 256, 0, stream>>>(seq, ln_g, ln_b, fc_w, fc_b,
                                          mlp_w, mlp_b, out);
}

// Round 7
// 12.910 us; speedup vs baseline: 1.7405x; 1.0197x over previous
//
#include <hip/hip_runtime.h>
#include <hip/hip_bf16.h>

#define D   256      // LN / fc input dim
#define F   128      // fc output dim
#define C   10       // classes
#define LN_EPS 1e-5f

typedef __attribute__((ext_vector_type(8))) short short8;   // 8 bf16 = 4 VGPR
typedef __attribute__((ext_vector_type(4))) short short4v;  // 4 bf16 = 2 VGPR
typedef __attribute__((ext_vector_type(4))) float f32x4;    // MFMA acc

__device__ __forceinline__ short f2bf(float f) {
    __hip_bfloat16 h = __float2bfloat16(f);          // RNE
    return *reinterpret_cast<short*>(&h);
}
__device__ __forceinline__ short8 pack8(float4 a, float4 b) {
    short8 r;
    r[0] = f2bf(a.x); r[1] = f2bf(a.y); r[2] = f2bf(a.z); r[3] = f2bf(a.w);
    r[4] = f2bf(b.x); r[5] = f2bf(b.y); r[6] = f2bf(b.z); r[7] = f2bf(b.w);
    return r;
}

__global__ __launch_bounds__(256, 1) void logreg_fused(
    const float* __restrict__ seq,   const float* __restrict__ ln_g,
    const float* __restrict__ ln_b,  const float* __restrict__ fc_w,
    const float* __restrict__ fc_b,  const float* __restrict__ mlp_w,
    const float* __restrict__ mlp_b, float* __restrict__ out)
{
    // A-tile: 16 rows x 256 k, bf16, XOR-swizzled (byte ^= r<<4). 8 KB.
    __shared__ short sxb[16 * D];
    // h-tile: 16 rows x 128 f, bf16, XOR-swizzled (byte ^= (r&7)<<4). 4 KB.
    __shared__ short shb[16 * F];

    const int t    = threadIdx.x;
    const int w    = t >> 6;
    const int lane = t & 63;
    const int q    = lane >> 4;   // k-subgroup 0..3
    const int col  = lane & 15;   // fragment row/col index
    const int rowbase = blockIdx.x * 16;
    const int obase   = 32 * w;   // wave's 32 fc output columns

    // ---------- Issue order: seq first (LN consumes soon), then weight prefetches.
    float4 v0 = ((const float4*)(seq + (size_t)(rowbase + 4 * w)     * D))[lane];
    float4 v1 = ((const float4*)(seq + (size_t)(rowbase + 4 * w + 1) * D))[lane];
    float4 v2 = ((const float4*)(seq + (size_t)(rowbase + 4 * w + 2) * D))[lane];
    float4 v3 = ((const float4*)(seq + (size_t)(rowbase + 4 * w + 3) * D))[lane];
    const float4 gv = ((const float4*)ln_g)[lane];
    const float4 bv = ((const float4*)ln_b)[lane];

    // fc_w B-fragments: lane supplies fc_w[obase+16ts+col][32kk+8q .. +8].
    float4 wf[2][16];
    #pragma unroll
    for (int ts = 0; ts < 2; ++ts) {
        const float4* __restrict__ wr =
            (const float4*)fc_w + (size_t)(obase + 16 * ts + col) * (D / 4) + 2 * q;
        #pragma unroll
        for (int kk = 0; kk < 8; ++kk) {
            wf[ts][2 * kk]     = wr[8 * kk];
            wf[ts][2 * kk + 1] = wr[8 * kk + 1];
        }
    }
    // mlp_w B-fragments (phase 3): lane supplies mlp_w[col][32kk+8q .. +8], col<10.
    float4 wf2[8] = {};
    if (col < C) {
        const float4* __restrict__ wr2 = (const float4*)(mlp_w + (size_t)col * F) + 2 * q;
        #pragma unroll
        for (int kk = 0; kk < 4; ++kk) {
            wf2[2 * kk]     = wr2[8 * kk];
            wf2[2 * kk + 1] = wr2[8 * kk + 1];
        }
    }
    const float mbv  = (col < C) ? mlp_b[col] : 0.0f;
    const float fcb0 = fc_b[obase + col];
    const float fcb1 = fc_b[obase + 16 + col];

    // ---------- Phase 1: LayerNorm (rows 4w..4w+3) under the prefetch. ----------
    {
        float4 vv[4] = {v0, v1, v2, v3};
        float s[4], qq[4];
        #pragma unroll
        for (int rr = 0; rr < 4; ++rr) {
            s[rr]  = vv[rr].x + vv[rr].y + vv[rr].z + vv[rr].w;
            qq[rr] = vv[rr].x * vv[rr].x + vv[rr].y * vv[rr].y
                   + vv[rr].z * vv[rr].z + vv[rr].w * vv[rr].w;
        }
        #pragma unroll
        for (int off = 32; off > 0; off >>= 1) {
            #pragma unroll
            for (int rr = 0; rr < 4; ++rr) {
                s[rr]  += __shfl_xor(s[rr],  off);
                qq[rr] += __shfl_xor(qq[rr], off);
            }
        }
        #pragma unroll
        for (int rr = 0; rr < 4; ++rr) {
            const int r = 4 * w + rr;
            const float m  = s[rr] * (1.0f / D);
            const float iv = rsqrtf(qq[rr] * (1.0f / D) - m * m + LN_EPS);
            short4v a;
            a[0] = f2bf((vv[rr].x - m) * iv * gv.x + bv.x);
            a[1] = f2bf((vv[rr].y - m) * iv * gv.y + bv.y);
            a[2] = f2bf((vv[rr].z - m) * iv * gv.z + bv.z);
            a[3] = f2bf((vv[rr].w - m) * iv * gv.w + bv.w);
            *(short4v*)((char*)sxb + (((r * 512) + lane * 8) ^ (r << 4))) = a;
        }
    }

    // Convert B-fragments fp32 -> bf16 in regs (fuses to v_cvt_pk_bf16_f32).
    short8 wb0[8], wb1[8], wb2[4];
    #pragma unroll
    for (int kk = 0; kk < 8; ++kk) {
        wb0[kk] = pack8(wf[0][2 * kk], wf[0][2 * kk + 1]);
        wb1[kk] = pack8(wf[1][2 * kk], wf[1][2 * kk + 1]);
    }
    #pragma unroll
    for (int kk = 0; kk < 4; ++kk)
        wb2[kk] = pack8(wf2[2 * kk], wf2[2 * kk + 1]);

    // LDS-only barrier (keeps remaining vmem in flight).
    asm volatile("s_waitcnt lgkmcnt(0)" ::: "memory");
    __builtin_amdgcn_s_barrier();

    // ---------- Phase 2: fc as MFMA. 16 rows x 32 cols per wave, K=256. ----------
    f32x4 acc0 = {0.f, 0.f, 0.f, 0.f};
    f32x4 acc1 = {0.f, 0.f, 0.f, 0.f};
    #pragma unroll
    for (int kk = 0; kk < 8; ++kk) {
        const int boff = ((col * 512) + kk * 64 + q * 16) ^ (col << 4);
        short8 a = *(const short8*)((const char*)sxb + boff);
        acc0 = __builtin_amdgcn_mfma_f32_16x16x32_bf16(a, wb0[kk], acc0, 0, 0, 0);
        acc1 = __builtin_amdgcn_mfma_f32_16x16x32_bf16(a, wb1[kk], acc1, 0, 0, 0);
    }

    // Epilogue: sigmoid, store h as bf16 (swizzled). All 64 lanes, rows 0..15.
    #pragma unroll
    for (int rg = 0; rg < 4; ++rg) {
        const int r  = q * 4 + rg;
        const float h0 = 1.0f / (1.0f + __expf(-(acc0[rg] + fcb0)));
        const float h1 = 1.0f / (1.0f + __expf(-(acc1[rg] + fcb1)));
        *(short*)((char*)shb + ((r * 256 + 2 * (obase + col))      ^ ((r & 7) << 4))) = f2bf(h0);
        *(short*)((char*)shb + ((r * 256 + 2 * (obase + 16 + col)) ^ ((r & 7) << 4))) = f2bf(h1);
    }

    asm volatile("s_waitcnt lgkmcnt(0)" ::: "memory");
    __builtin_amdgcn_s_barrier();

    // ---------- Phase 3: mlp 128->10 as one MFMA chain (K=128, 4 steps). ----------
    // All waves compute (redundant, identical); wave 0 stores.
    {
        f32x4 acc2 = {0.f, 0.f, 0.f, 0.f};
        #pragma unroll
        for (int kk = 0; kk < 4; ++kk) {
            const int boff = (col * 256 + kk * 64 + q * 16) ^ ((col & 7) << 4);
            short8 a = *(const short8*)((const char*)shb + boff);
            acc2 = __builtin_amdgcn_mfma_f32_16x16x32_bf16(a, wb2[kk], acc2, 0, 0, 0);
        }
        if (w == 0 && col < C) {
            #pragma unroll
            for (int rg = 0; rg < 4; ++rg) {
                const int r = q * 4 + rg;
                out[(size_t)(rowbase + r) * C + col] = acc2[rg] + mbv;
            }
        }
    }
}

extern "C" void kernel_launch(void* const* d_in, const int* in_sizes, int n_in,
                              void* d_out, int out_size, void* d_ws, size_t ws_size,
                              hipStream_t stream)
{
    const float* seq   = (const float*)d_in[0];
    const float* ln_g  = (const float*)d_in[1];
    const float* ln_b  = (const float*)d_in[2];
    const float* fc_w  = (const float*)d_in[3];
    const float* fc_b  = (const float*)d_in[4];
    const float* mlp_w = (const float*)d_in[5];
    const float* mlp_b = (const float*)d_in[6];
    float* out = (float*)d_out;

    // 1408 rows = 88 blocks * 16 rows; one block per CU, full 16-row MFMA tiles.
    logreg_fused<<<88, 256, 0, stream>>>(seq, ln_g, ln_b, fc_w, fc_b,
                                         mlp_w, mlp_b, out);
}